// Round 2
// baseline (1998.589 us; speedup 1.0000x reference)
//
#include <hip/hip_runtime.h>

#define B_ 16
#define T_ 1000
#define F_ 257
#define TT 8
#define TFR 32
// extended tile dims
#define XT (TT+3)    // 11 rows of x
#define XF (TFR+12)  // 44 cols of x
#define HT (TT+2)    // 10 rows of h
#define HF (TFR+8)   // 40 cols of h
#define PT (TT+2)    // 10 rows of xp
#define PF (TFR+8)   // 40 cols of xp
#define RT (TT+1)    // 9 rows of rh
#define RF (TFR+4)   // 36 cols of rh

__device__ __forceinline__ float fsigmoid(float v) { return 1.0f / (1.0f + __expf(-v)); }
__device__ __forceinline__ float ftanh(float v)    { return 2.0f / (1.0f + __expf(-2.0f * v)) - 1.0f; }
__device__ __forceinline__ float felu(float v)     { return v > 0.0f ? v : (__expf(v) - 1.0f); }

extern "C" __global__ __launch_bounds__(256, 2)
void gru_fused(const float* __restrict__ x, const float* __restrict__ h,
               const float* __restrict__ pre_w, const float* __restrict__ pre_b,
               const float* __restrict__ xz_w, const float* __restrict__ xz_b,
               const float* __restrict__ xr_w, const float* __restrict__ xr_b,
               const float* __restrict__ xn_w, const float* __restrict__ xn_b,
               const float* __restrict__ hz_w, const float* __restrict__ hz_b,
               const float* __restrict__ hr_w, const float* __restrict__ hr_b,
               const float* __restrict__ hn_w, const float* __restrict__ hn_b,
               float* __restrict__ out)
{
    // weights transposed to [ci][kt][kf][co] (co contiguous for the inner loop)
    __shared__ float wpre[4*2*5*8];
    __shared__ float wxz[8*2*5*8], whz[8*2*5*8];
    __shared__ float wxr[8*2*5*8], whr[8*2*5*8];
    __shared__ float wxn[8*2*5*8], whn[8*2*5*8];
    __shared__ float bpre[8], bz[8], br[8], bn[8];
    __shared__ float sx [4][XT][XF];
    __shared__ float sh [8][HT][HF];
    __shared__ float sxp[8][PT][PF];
    __shared__ float srh[8][RT][RF];

    const int tid = threadIdx.x;
    const int f0 = blockIdx.x * TFR;
    const int t0 = blockIdx.y * TT;
    const int b  = blockIdx.z;

    // ---- phase 0: weights -> LDS (transpose OIHW -> [ci][kt][kf][co]) ----
    for (int idx = tid; idx < 320; idx += 256) {
        int co = idx & 7; int r = idx >> 3;
        int kf = r % 5; r /= 5; int kt = r & 1; int ci = r >> 1;
        wpre[idx] = pre_w[((co*4+ci)*2+kt)*5+kf];
    }
    {
        const float* srcs[6] = {xz_w, hz_w, xr_w, hr_w, xn_w, hn_w};
        float*       dsts[6] = {wxz,  whz,  wxr,  whr,  wxn,  whn};
        #pragma unroll
        for (int a = 0; a < 6; ++a) {
            const float* s = srcs[a];
            float*       d = dsts[a];
            for (int idx = tid; idx < 640; idx += 256) {
                int co = idx & 7; int r = idx >> 3;
                int kf = r % 5; r /= 5; int kt = r & 1; int ci = r >> 1;
                d[idx] = s[((co*8+ci)*2+kt)*5+kf];
            }
        }
    }
    if (tid < 8) {
        bpre[tid] = pre_b[tid];
        bz[tid]   = xz_b[tid] + hz_b[tid];
        br[tid]   = xr_b[tid] + hr_b[tid];
        bn[tid]   = xn_b[tid] + hn_b[tid];
    }

    // ---- phase 1: stage x and h tiles (zero-fill halo out of range) ----
    for (int idx = tid; idx < 4*XT*XF; idx += 256) {
        int ff = idx % XF; int r = idx / XF; int tt = r % XT; int ci = r / XT;
        int gt = t0 - 3 + tt, gf = f0 - 6 + ff;
        float v = 0.0f;
        if (gt >= 0 && gf >= 0 && gf < F_) v = x[((b*4+ci)*T_+gt)*F_+gf];
        sx[ci][tt][ff] = v;
    }
    for (int idx = tid; idx < 8*HT*HF; idx += 256) {
        int ff = idx % HF; int r = idx / HF; int tt = r % HT; int ci = r / HT;
        int gt = t0 - 2 + tt, gf = f0 - 4 + ff;
        float v = 0.0f;
        if (gt >= 0 && gf >= 0 && gf < F_) v = h[((b*8+ci)*T_+gt)*F_+gf];
        sh[ci][tt][ff] = v;
    }
    __syncthreads();

    // ---- phase 2: xp = elu(pre-conv(x)) on extended 10x40 region ----
    // NOTE: the z/r/n convs zero-PAD xp — xp outside [0,T)x[0,F) must be 0,
    // not elu(conv(zero-padded x)). sxp[*][i][j] is global (t0-2+i, f0-4+j).
    for (int pos = tid; pos < PT*PF; pos += 256) {
        int i = pos / PF, j = pos % PF;
        int gt = t0 - 2 + i, gf = f0 - 4 + j;
        bool valid = (gt >= 0) && (gf >= 0) && (gf < F_);
        float acc[8];
        #pragma unroll
        for (int co = 0; co < 8; ++co) acc[co] = bpre[co];
        #pragma unroll 1
        for (int ci = 0; ci < 4; ++ci) {
            #pragma unroll
            for (int kt = 0; kt < 2; ++kt) {
                #pragma unroll
                for (int kf = 0; kf < 5; ++kf) {
                    float v = sx[ci][i+kt][j+kf];
                    const float* w = &wpre[((ci*2+kt)*5+kf)*8];
                    #pragma unroll
                    for (int co = 0; co < 8; ++co) acc[co] += v * w[co];
                }
            }
        }
        #pragma unroll
        for (int co = 0; co < 8; ++co) sxp[co][i][j] = valid ? felu(acc[co]) : 0.0f;
    }
    __syncthreads();

    // ---- phase 3: rh = sigmoid(conv(xp,xr)+conv(h,hr)+b) * h on 9x36 region ----
    // rh OOR positions are 0 automatically because sh is zero-filled OOR.
    for (int pos = tid; pos < RT*RF; pos += 256) {
        int i = pos / RF, j = pos % RF;
        float acc[8];
        #pragma unroll
        for (int co = 0; co < 8; ++co) acc[co] = br[co];
        #pragma unroll 1
        for (int ci = 0; ci < 8; ++ci) {
            #pragma unroll
            for (int kt = 0; kt < 2; ++kt) {
                #pragma unroll
                for (int kf = 0; kf < 5; ++kf) {
                    float vx = sxp[ci][i+kt][j+kf];
                    float vh = sh [ci][i+kt][j+kf];
                    const int wi = ((ci*2+kt)*5+kf)*8;
                    #pragma unroll
                    for (int co = 0; co < 8; ++co)
                        acc[co] += vx * wxr[wi+co] + vh * whr[wi+co];
                }
            }
        }
        #pragma unroll
        for (int co = 0; co < 8; ++co) {
            float r = fsigmoid(acc[co]);
            srh[co][i][j] = r * sh[co][i+1][j+2];
        }
    }
    __syncthreads();

    // ---- phase 4: z, n, out at center 8x32 pixels (1 pixel/thread) ----
    {
        int i = tid >> 5, j = tid & 31;
        float zacc[8], nacc[8];
        #pragma unroll
        for (int co = 0; co < 8; ++co) { zacc[co] = bz[co]; nacc[co] = bn[co]; }
        #pragma unroll 1
        for (int ci = 0; ci < 8; ++ci) {
            #pragma unroll
            for (int kt = 0; kt < 2; ++kt) {
                #pragma unroll
                for (int kf = 0; kf < 5; ++kf) {
                    float vx = sxp[ci][i+1+kt][j+2+kf];
                    float vh = sh [ci][i+1+kt][j+2+kf];
                    float vr = srh[ci][i+kt][j+kf];
                    const int wi = ((ci*2+kt)*5+kf)*8;
                    #pragma unroll
                    for (int co = 0; co < 8; ++co) {
                        zacc[co] += vx * wxz[wi+co] + vh * whz[wi+co];
                        nacc[co] += vx * wxn[wi+co] + vr * whn[wi+co];
                    }
                }
            }
        }
        int gf = f0 + j;
        if (gf < F_) {
            int gt = t0 + i;
            #pragma unroll
            for (int co = 0; co < 8; ++co) {
                float z  = fsigmoid(zacc[co]);
                float n  = ftanh(nacc[co]);
                float hc = sh[co][i+2][j+4];
                out[((b*8+co)*T_+gt)*F_+gf] = (1.0f - z) * hc + z * n;
            }
        }
    }
}

extern "C" void kernel_launch(void* const* d_in, const int* in_sizes, int n_in,
                              void* d_out, int out_size, void* d_ws, size_t ws_size,
                              hipStream_t stream) {
    const float* x     = (const float*)d_in[0];
    const float* h     = (const float*)d_in[1];
    const float* pre_w = (const float*)d_in[2];
    const float* pre_b = (const float*)d_in[3];
    const float* xz_w  = (const float*)d_in[4];
    const float* xz_b  = (const float*)d_in[5];
    const float* xr_w  = (const float*)d_in[6];
    const float* xr_b  = (const float*)d_in[7];
    const float* xn_w  = (const float*)d_in[8];
    const float* xn_b  = (const float*)d_in[9];
    const float* hz_w  = (const float*)d_in[10];
    const float* hz_b  = (const float*)d_in[11];
    const float* hr_w  = (const float*)d_in[12];
    const float* hr_b  = (const float*)d_in[13];
    const float* hn_w  = (const float*)d_in[14];
    const float* hn_b  = (const float*)d_in[15];
    float* out = (float*)d_out;

    dim3 grid((F_ + TFR - 1) / TFR, T_ / TT, B_);  // 9 x 125 x 16
    dim3 block(256);
    gru_fused<<<grid, block, 0, stream>>>(x, h,
        pre_w, pre_b, xz_w, xz_b, xr_w, xr_b, xn_w, xn_b,
        hz_w, hz_b, hr_w, hr_b, hn_w, hn_b, out);
}

// Round 3
// 553.302 us; speedup vs baseline: 3.6121x; 3.6121x over previous
//
#include <hip/hip_runtime.h>

#define T_ 1000
#define F_ 257

// LDS tile geometry (center tile 8 t-rows x 32 f-cols)
#define SX_T 11
#define SX_W 44
#define SH_T 10
#define SH_W 40
#define SP_T 10
#define SP_W 48
#define SR_T 9
#define SR_W 48

typedef short bf16x8 __attribute__((ext_vector_type(8)));
typedef short bf16x4 __attribute__((ext_vector_type(4)));
typedef float f32x4  __attribute__((ext_vector_type(4)));

__device__ __forceinline__ int imin(int a, int b) { return a < b ? a : b; }

__device__ __forceinline__ unsigned short f2bf(float f) {
    unsigned int u = __float_as_uint(f);
    u += 0x7fffu + ((u >> 16) & 1u);          // round-to-nearest-even
    return (unsigned short)(u >> 16);
}
__device__ __forceinline__ float bf2f(unsigned short h) {
    return __uint_as_float(((unsigned int)h) << 16);
}
__device__ __forceinline__ float fsigmoid(float v) { return 1.0f / (1.0f + __expf(-v)); }
__device__ __forceinline__ float ftanh(float v)    { return 2.0f / (1.0f + __expf(-2.0f * v)) - 1.0f; }

extern "C" __global__ __launch_bounds__(256, 4)
void gru_mfma(const float* __restrict__ x, const float* __restrict__ h,
              const float* __restrict__ pre_w, const float* __restrict__ pre_b,
              const float* __restrict__ xz_w, const float* __restrict__ xz_b,
              const float* __restrict__ xr_w, const float* __restrict__ xr_b,
              const float* __restrict__ xn_w, const float* __restrict__ xn_b,
              const float* __restrict__ hz_w, const float* __restrict__ hz_b,
              const float* __restrict__ hr_w, const float* __restrict__ hr_b,
              const float* __restrict__ hn_w, const float* __restrict__ hn_b,
              float* __restrict__ out)
{
    // B^T weight tables [n][k] (bf16). k = tap*8+ci (tap = kt*5+kf), h-taps at +80.
    __shared__ __align__(16) unsigned short BZX[16][160]; // n<8: xz|hz ; n>=8: xn|0
    __shared__ __align__(16) unsigned short BR [16][160]; // n<8: xr|hr ; n>=8: 0
    __shared__ __align__(16) unsigned short BHN[16][96];  // n>=8: hn (taps<10) ; else 0
    __shared__ __align__(16) unsigned short BPR[16][64];  // n<8: pre (k=tap*4+ci, taps<10)
    // channel-last bf16 activation tiles
    __shared__ __align__(16) unsigned short sx [SX_T][SX_W][4];
    __shared__ __align__(16) unsigned short sh [SH_T][SH_W][8];
    __shared__ __align__(16) unsigned short sxp[SP_T][SP_W][8];
    __shared__ __align__(16) unsigned short srh[SR_T][SR_W][8];

    const int tid  = threadIdx.x;
    const int lane = tid & 63;
    const int wave = tid >> 6;
    const int am   = lane & 15;  // A-fragment row (pixel within 16-seg)
    const int q    = lane >> 4;  // quad
    const int c    = am;         // C/D column (output channel) in epilogues
    const int f0   = blockIdx.x * 32;
    const int t0   = blockIdx.y * 8;
    const int b    = blockIdx.z;

    // ---- zero weight tables ----
    for (int i = tid; i < 16*160; i += 256) { ((unsigned short*)BZX)[i] = 0; ((unsigned short*)BR)[i] = 0; }
    for (int i = tid; i < 16*96;  i += 256) ((unsigned short*)BHN)[i] = 0;
    for (int i = tid; i < 16*64;  i += 256) ((unsigned short*)BPR)[i] = 0;
    __syncthreads();

    // ---- fill weight tables (global OIHW -> [n][k]) ----
    for (int i = tid; i < 640; i += 256) {
        int co = i / 80, ci = (i / 10) % 8, kt = (i / 5) % 2, kf = i % 5;
        int k = (kt * 5 + kf) * 8 + ci;
        BZX[co][k]        = f2bf(xz_w[i]);
        BZX[8 + co][k]    = f2bf(xn_w[i]);
        BZX[co][80 + k]   = f2bf(hz_w[i]);
        BR [co][k]        = f2bf(xr_w[i]);
        BR [co][80 + k]   = f2bf(hr_w[i]);
        BHN[8 + co][k]    = f2bf(hn_w[i]);
    }
    for (int i = tid; i < 320; i += 256) {
        int co = i / 40, ci = (i / 10) % 4, kt = (i / 5) % 2, kf = i % 5;
        BPR[co][(kt * 5 + kf) * 4 + ci] = f2bf(pre_w[i]);
    }

    // ---- stage x (bf16 channel-last, zero OOR) ----
    for (int i = tid; i < SX_T * SX_W; i += 256) {
        int r = i / SX_W, col = i - r * SX_W;
        int gt = t0 - 3 + r, gf = f0 - 6 + col;
        ushort4 pk = {0, 0, 0, 0};
        if (gt >= 0 && gf >= 0 && gf < F_) {
            const float* p = x + ((size_t)(b * 4) * T_ + gt) * F_ + gf;
            pk.x = f2bf(p[0]);
            pk.y = f2bf(p[257000]);
            pk.z = f2bf(p[514000]);
            pk.w = f2bf(p[771000]);
        }
        *(ushort4*)&sx[r][col][0] = pk;
    }
    // ---- stage h ----
    for (int i = tid; i < SH_T * SH_W; i += 256) {
        int r = i / SH_W, col = i - r * SH_W;
        int gt = t0 - 2 + r, gf = f0 - 4 + col;
        ushort4 p0 = {0, 0, 0, 0}, p1 = {0, 0, 0, 0};
        if (gt >= 0 && gf >= 0 && gf < F_) {
            const float* p = h + ((size_t)(b * 8) * T_ + gt) * F_ + gf;
            p0.x = f2bf(p[0]);
            p0.y = f2bf(p[257000]);
            p0.z = f2bf(p[2 * 257000]);
            p0.w = f2bf(p[3 * 257000]);
            p1.x = f2bf(p[4 * 257000]);
            p1.y = f2bf(p[5 * 257000]);
            p1.z = f2bf(p[6 * 257000]);
            p1.w = f2bf(p[7 * 257000]);
        }
        *(ushort4*)&sh[r][col][0] = p0;
        *(ushort4*)&sh[r][col][4] = p1;
    }

    // ---- per-lane accumulator biases (col = channel) ----
    float bias4 = (c < 8) ? (xz_b[c] + hz_b[c]) : (xn_b[c - 8] + hn_b[c - 8]);
    float bias3 = (c < 8) ? (xr_b[c] + hr_b[c]) : 0.0f;
    float bias2 = (c < 8) ? pre_b[c] : 0.0f;
    __syncthreads();

    // ================= phase 2: xp = elu(pre-conv(x)), 10 x 48 region =================
    {
        bf16x8 fpre[2];
        #pragma unroll
        for (int s = 0; s < 2; ++s) fpre[s] = *(const bf16x8*)&BPR[c][s * 32 + q * 8];
        for (int u = wave; u < 30; u += 4) {
            int r2 = u / 3, fs = u - r2 * 3;
            f32x4 acc = {bias2, bias2, bias2, bias2};
            #pragma unroll
            for (int s = 0; s < 2; ++s) {
                int ta = 8 * s + 2 * q;
                int tb = ta + 1;
                int t1 = (ta < 10) ? ta : 0;          // padded taps -> clamp (weights are 0)
                int t2 = (tb < 10) ? tb : 0;
                int kt1 = (t1 >= 5), kf1 = t1 - kt1 * 5;
                int kt2 = (t2 >= 5), kf2 = t2 - kt2 * 5;
                int c1 = imin(fs * 16 + am + kf1, SX_W - 1);
                int c2 = imin(fs * 16 + am + kf2, SX_W - 1);
                union { bf16x8 v; bf16x4 hh[2]; } a;
                a.hh[0] = *(const bf16x4*)&sx[r2 + kt1][c1][0];
                a.hh[1] = *(const bf16x4*)&sx[r2 + kt2][c2][0];
                acc = __builtin_amdgcn_mfma_f32_16x16x32_bf16(a.v, fpre[s], acc, 0, 0, 0);
            }
            int gt = t0 - 2 + r2;
            #pragma unroll
            for (int rr = 0; rr < 4; ++rr) {
                int pix = q * 4 + rr;
                int gf = f0 - 4 + fs * 16 + pix;
                bool v = (gt >= 0) && (gf >= 0) && (gf < F_);
                float val = acc[rr];
                val = val > 0.0f ? val : (__expf(val) - 1.0f);
                if (c < 8) sxp[r2][fs * 16 + pix][c] = v ? f2bf(val) : (unsigned short)0;
            }
        }
    }
    __syncthreads();

    // ================= phase 3: rh = sigmoid(r-conv) * h, 9 x 48 region =================
    {
        bf16x8 fr[5];
        #pragma unroll
        for (int s = 0; s < 5; ++s) fr[s] = *(const bf16x8*)&BR[c][s * 32 + q * 8];
        for (int u = wave; u < 27; u += 4) {
            int r3 = u / 3, fs = u - r3 * 3;
            f32x4 acc = {bias3, bias3, bias3, bias3};
            #pragma unroll
            for (int s = 0; s < 5; ++s) {
                int tap = s * 4 + q;
                const unsigned short* src;
                if (tap < 10) {
                    int kt = (tap >= 5), kf = tap - kt * 5;
                    src = &sxp[r3 + kt][imin(fs * 16 + am + kf, SP_W - 1)][0];
                } else {
                    int tt = tap - 10;
                    int kt = (tt >= 5), kf = tt - kt * 5;
                    src = &sh[r3 + kt][imin(fs * 16 + am + kf, SH_W - 1)][0];
                }
                bf16x8 a = *(const bf16x8*)src;
                acc = __builtin_amdgcn_mfma_f32_16x16x32_bf16(a, fr[s], acc, 0, 0, 0);
            }
            #pragma unroll
            for (int rr = 0; rr < 4; ++rr) {
                int pix = q * 4 + rr;
                int hcol = imin(2 + fs * 16 + pix, SH_W - 1);
                if (c < 8) {
                    float hv = bf2f(sh[r3 + 1][hcol][c]);
                    float rv = fsigmoid(acc[rr]);
                    srh[r3][fs * 16 + pix][c] = f2bf(rv * hv);
                }
            }
        }
    }
    __syncthreads();

    // ================= phase 4: z | n, center 8 x 32, write out =================
    {
        bf16x8 fzx[5], fhn[3];
        #pragma unroll
        for (int s = 0; s < 5; ++s) fzx[s] = *(const bf16x8*)&BZX[c][s * 32 + q * 8];
        #pragma unroll
        for (int s = 0; s < 3; ++s) fhn[s] = *(const bf16x8*)&BHN[c][s * 32 + q * 8];
        for (int u = wave; u < 16; u += 4) {
            int i4 = u >> 1, fs = u & 1;
            f32x4 acc = {bias4, bias4, bias4, bias4};
            #pragma unroll
            for (int s = 0; s < 5; ++s) {
                int tap = s * 4 + q;
                const unsigned short* src;
                if (tap < 10) {
                    int kt = (tap >= 5), kf = tap - kt * 5;
                    src = &sxp[i4 + 1 + kt][2 + fs * 16 + am + kf][0];
                } else {
                    int tt = tap - 10;
                    int kt = (tt >= 5), kf = tt - kt * 5;
                    src = &sh[i4 + 1 + kt][2 + fs * 16 + am + kf][0];
                }
                bf16x8 a = *(const bf16x8*)src;
                acc = __builtin_amdgcn_mfma_f32_16x16x32_bf16(a, fzx[s], acc, 0, 0, 0);
            }
            #pragma unroll
            for (int s = 0; s < 3; ++s) {
                int tap = s * 4 + q;
                int tt = (tap < 10) ? tap : 0;        // taps 10,11 have zero weights
                int kt = (tt >= 5), kf = tt - kt * 5;
                bf16x8 a = *(const bf16x8*)&srh[i4 + kt][fs * 16 + am + kf][0];
                acc = __builtin_amdgcn_mfma_f32_16x16x32_bf16(a, fhn[s], acc, 0, 0, 0);
            }
            int gt = t0 + i4;
            #pragma unroll
            for (int rr = 0; rr < 4; ++rr) {
                float other = __shfl_xor(acc[rr], 8);   // all lanes: swap z <-> n logits
                if (c < 8) {
                    int pix = q * 4 + rr;
                    int gf = f0 + fs * 16 + pix;
                    if (gf < F_) {
                        float z = fsigmoid(acc[rr]);
                        float n = ftanh(other);
                        float hv = bf2f(sh[i4 + 2][4 + fs * 16 + pix][c]);
                        out[((size_t)(b * 8 + c) * T_ + gt) * F_ + gf] = (1.0f - z) * hv + z * n;
                    }
                }
            }
        }
    }
}

extern "C" void kernel_launch(void* const* d_in, const int* in_sizes, int n_in,
                              void* d_out, int out_size, void* d_ws, size_t ws_size,
                              hipStream_t stream) {
    const float* x     = (const float*)d_in[0];
    const float* h     = (const float*)d_in[1];
    const float* pre_w = (const float*)d_in[2];
    const float* pre_b = (const float*)d_in[3];
    const float* xz_w  = (const float*)d_in[4];
    const float* xz_b  = (const float*)d_in[5];
    const float* xr_w  = (const float*)d_in[6];
    const float* xr_b  = (const float*)d_in[7];
    const float* xn_w  = (const float*)d_in[8];
    const float* xn_b  = (const float*)d_in[9];
    const float* hz_w  = (const float*)d_in[10];
    const float* hz_b  = (const float*)d_in[11];
    const float* hr_w  = (const float*)d_in[12];
    const float* hr_b  = (const float*)d_in[13];
    const float* hn_w  = (const float*)d_in[14];
    const float* hn_b  = (const float*)d_in[15];
    float* out = (float*)d_out;

    dim3 grid(9, 125, 16);   // ceil(257/32) x 1000/8 x B
    dim3 block(256);
    gru_mfma<<<grid, block, 0, stream>>>(x, h,
        pre_w, pre_b, xz_w, xz_b, xr_w, xr_b, xn_w, xn_b,
        hz_w, hz_b, hr_w, hr_b, hn_w, hn_b, out);
}